// Round 1
// baseline (115.889 us; speedup 1.0000x reference)
//
#include <hip/hip_runtime.h>
#include <math.h>

#define B_   16
#define N_   256
#define F_   64
#define FP_  16
#define H_   128
#define DMAX 1.7320508075688772f   // sqrt(3): r in [0,1]^3

__device__ __forceinline__ float sp(float x) {
    // numerically stable softplus: max(x,0) + log1p(exp(-|x|))
    return fmaxf(x, 0.0f) + log1pf(expf(-fabsf(x)));
}

// -------- Kernel 1: tabulate d -> softplus(MLP(d)) into lut[T][F_] --------
// grid = T blocks, 128 threads
__global__ void pp_build_lut(const float* __restrict__ mp_w1,
                             const float* __restrict__ mp_b1,
                             const float* __restrict__ mp_w2,
                             const float* __restrict__ mp_b2,
                             float* __restrict__ lut, int T, float dstep) {
    __shared__ float hid[H_];
    const int t   = blockIdx.x;
    const int tid = threadIdx.x;
    const float d = t * dstep;
    hid[tid] = sp(fmaf(d, mp_w1[tid], mp_b1[tid]));   // tid in [0,128)
    __syncthreads();
    if (tid < F_) {
        float z = mp_b2[tid];
        #pragma unroll 8
        for (int h = 0; h < H_; ++h)
            z = fmaf(hid[h], mp_w2[h * F_ + tid], z);
        lut[(size_t)t * F_ + tid] = sp(z);
    }
}

// -------- Kernel 2: per (b,i) row: f_bar -> pointwise MLP -> out ----------
// grid = B*N blocks, 256 threads
__global__ __launch_bounds__(256) void pp_predict(
        const float* __restrict__ r,   const float* __restrict__ fb,
        const float* __restrict__ lut,
        const float* __restrict__ pc_w1, const float* __restrict__ pc_b1,
        const float* __restrict__ pc_w2, const float* __restrict__ pc_b2,
        float* __restrict__ out, int T, float inv_step) {
    const int blk = blockIdx.x;        // b*N + i
    const int b   = blk >> 8;          // N_ == 256
    const int i   = blk & (N_ - 1);
    const int tid = threadIdx.x;

    __shared__ float sh_fi[N_];          // continuous LUT index per j
    __shared__ float sh_acc[16][F_];     // partial f_bar per j-group
    __shared__ float sh_fbar[F_];
    __shared__ float sh_h2[H_];

    // ---- phase 1: pairwise distances for row i ----
    {
        const float xi = r[(b * N_ + i) * 3 + 0];
        const float yi = r[(b * N_ + i) * 3 + 1];
        const float zi = r[(b * N_ + i) * 3 + 2];
        const int j = tid;
        const float dx = xi - r[(b * N_ + j) * 3 + 0];
        const float dy = yi - r[(b * N_ + j) * 3 + 1];
        const float dz = zi - r[(b * N_ + j) * 3 + 2];
        const float sq = fmaf(dx, dx, fmaf(dy, dy, dz * dz));
        const float d  = sq > 0.0f ? sqrtf(sq) : 0.0f;
        sh_fi[j] = fminf(d * inv_step, (float)(T - 1));
    }
    __syncthreads();

    // ---- phase 2: f_bar[f] = sum_j lerp(lut, d_ij)[f] * fb[b,j,f] ----
    const int fq = tid & 15;            // float4 group: f = fq*4 .. fq*4+3
    const int jg = tid >> 4;            // 16 groups of 16 j
    float4 acc = make_float4(0.f, 0.f, 0.f, 0.f);
    const float* fbrow = fb + (size_t)b * N_ * F_;
    #pragma unroll 4
    for (int jj = 0; jj < 16; ++jj) {
        const int j = jg * 16 + jj;
        const float fi = sh_fi[j];
        int idx = (int)fi;
        if (idx > T - 2) idx = T - 2;
        const float frac = fi - (float)idx;
        const float4 L0 = *(const float4*)(lut + (size_t)idx * F_ + fq * 4);
        const float4 L1 = *(const float4*)(lut + (size_t)(idx + 1) * F_ + fq * 4);
        const float4 fv = *(const float4*)(fbrow + j * F_ + fq * 4);
        acc.x = fmaf(fmaf(frac, L1.x - L0.x, L0.x), fv.x, acc.x);
        acc.y = fmaf(fmaf(frac, L1.y - L0.y, L0.y), fv.y, acc.y);
        acc.z = fmaf(fmaf(frac, L1.z - L0.z, L0.z), fv.z, acc.z);
        acc.w = fmaf(fmaf(frac, L1.w - L0.w, L0.w), fv.w, acc.w);
    }
    *(float4*)(&sh_acc[jg][fq * 4]) = acc;
    __syncthreads();

    if (tid < F_) {
        float s = 0.0f;
        #pragma unroll
        for (int g = 0; g < 16; ++g) s += sh_acc[g][tid];
        sh_fbar[tid] = sp(s);
    }
    __syncthreads();

    // ---- phase 3: h2[h] = sp(sum_f fbar[f] * pc_w1[f,h] + b1[h]) ----
    if (tid < H_) {
        float z = pc_b1[tid];
        #pragma unroll 8
        for (int f = 0; f < F_; ++f)
            z = fmaf(sh_fbar[f], pc_w1[f * H_ + tid], z);
        sh_h2[tid] = sp(z);
    }
    __syncthreads();

    // ---- phase 4: out[p] = sp(sum_h h2[h] * pc_w2[h,p] + b2[p]) ----
    if (tid < FP_) {
        float z = pc_b2[tid];
        #pragma unroll 8
        for (int h = 0; h < H_; ++h)
            z = fmaf(sh_h2[h], pc_w2[h * FP_ + tid], z);
        out[(size_t)blk * FP_ + tid] = sp(z);
    }
}

extern "C" void kernel_launch(void* const* d_in, const int* in_sizes, int n_in,
                              void* d_out, int out_size, void* d_ws, size_t ws_size,
                              hipStream_t stream) {
    const float* r_batch = (const float*)d_in[0];
    const float* f_batch = (const float*)d_in[1];
    const float* mp_w1   = (const float*)d_in[2];
    const float* mp_b1   = (const float*)d_in[3];
    const float* mp_w2   = (const float*)d_in[4];
    const float* mp_b2   = (const float*)d_in[5];
    const float* pc_w1   = (const float*)d_in[6];
    const float* pc_b1   = (const float*)d_in[7];
    const float* pc_w2   = (const float*)d_in[8];
    const float* pc_b2   = (const float*)d_in[9];
    float* out = (float*)d_out;
    float* lut = (float*)d_ws;

    // LUT resolution: 2048 entries (512 KB) or as much workspace as we have
    int T = (int)(ws_size / (F_ * sizeof(float)));
    if (T > 2048) T = 2048;
    if (T < 2)    T = 2;  // defensive; should never trigger
    const float dstep    = DMAX / (float)(T - 1);
    const float inv_step = (float)(T - 1) / DMAX;

    pp_build_lut<<<T, H_, 0, stream>>>(mp_w1, mp_b1, mp_w2, mp_b2, lut, T, dstep);
    pp_predict<<<B_ * N_, 256, 0, stream>>>(r_batch, f_batch, lut,
                                            pc_w1, pc_b1, pc_w2, pc_b2,
                                            out, T, inv_step);
}

// Round 2
// 104.321 us; speedup vs baseline: 1.1109x; 1.1109x over previous
//
#include <hip/hip_runtime.h>
#include <math.h>

#define B_   16
#define N_   256
#define F_   64
#define FP_  16
#define H_   128
#define T_   192                   // LUT entries: 192*64*4 = 48 KB (LDS-resident)
#define I_   4                     // i-rows per block
#define DMAX 1.7320508075688772f   // sqrt(3): r in [0,1]^3

__device__ __forceinline__ float sp(float x) {
    // numerically stable softplus: max(x,0) + log1p(exp(-|x|))
    return fmaxf(x, 0.0f) + log1pf(expf(-fabsf(x)));
}

// -------- Kernel 1: tabulate d -> softplus(MLP(d)) into lut[T_][F_] --------
// grid = T_ blocks, 128 threads
__global__ void pp_build_lut(const float* __restrict__ mp_w1,
                             const float* __restrict__ mp_b1,
                             const float* __restrict__ mp_w2,
                             const float* __restrict__ mp_b2,
                             float* __restrict__ lut, float dstep) {
    __shared__ float hid[H_];
    const int t   = blockIdx.x;
    const int tid = threadIdx.x;
    const float d = t * dstep;
    hid[tid] = sp(fmaf(d, mp_w1[tid], mp_b1[tid]));   // tid in [0,128)
    __syncthreads();
    if (tid < F_) {
        float z = mp_b2[tid];
        #pragma unroll 8
        for (int h = 0; h < H_; ++h)
            z = fmaf(hid[h], mp_w2[h * F_ + tid], z);
        lut[(size_t)t * F_ + tid] = sp(z);
    }
}

// -------- Kernel 2: LDS-resident LUT, 4 rows per block --------------------
// grid = B_*N_/I_ = 1024 blocks, 256 threads
__global__ __launch_bounds__(256) void pp_predict(
        const float* __restrict__ r,   const float* __restrict__ fb,
        const float* __restrict__ lut,
        const float* __restrict__ pc_w1, const float* __restrict__ pc_b1,
        const float* __restrict__ pc_w2, const float* __restrict__ pc_b2,
        float* __restrict__ out, float inv_step) {
    const int tid   = threadIdx.x;
    const int b     = blockIdx.x >> 6;          // 64 blocks per batch
    const int itile = (blockIdx.x & 63) << 2;   // first of 4 i-rows

    __shared__ float s_lut[T_ * F_];     // 48 KB
    __shared__ float s_scr[I_ * N_];     // 4 KB: fi -> partials -> h2 (sequenced by barriers)
    __shared__ float s_fbar[I_ * F_];    // 1 KB

    // ---- stage LUT into LDS (12288 floats / 256 thr = 12 x float4) ----
    {
        const float4* src = (const float4*)lut;
        float4*       dst = (float4*)s_lut;
        #pragma unroll
        for (int k = 0; k < (T_ * F_ / 4) / 256; ++k)
            dst[k * 256 + tid] = src[k * 256 + tid];
    }

    // ---- distances for the 4 rows: s_scr[ii*256 + j] = continuous LUT idx ----
    {
        const int j = tid;
        const float xj = r[(b * N_ + j) * 3 + 0];
        const float yj = r[(b * N_ + j) * 3 + 1];
        const float zj = r[(b * N_ + j) * 3 + 2];
        #pragma unroll
        for (int ii = 0; ii < I_; ++ii) {
            const int i = itile + ii;
            const float dx = r[(b * N_ + i) * 3 + 0] - xj;
            const float dy = r[(b * N_ + i) * 3 + 1] - yj;
            const float dz = r[(b * N_ + i) * 3 + 2] - zj;
            const float sq = fmaf(dx, dx, fmaf(dy, dy, dz * dz));
            const float d  = sq > 0.0f ? sqrtf(sq) : 0.0f;
            // clamp so (int)fi <= T_-2 and frac stays in [0,1)
            s_scr[ii * N_ + j] = fminf(d * inv_step, (float)(T_ - 1) - 1e-3f);
        }
    }
    __syncthreads();

    // ---- main loop: acc[ii][f4] += lerp(lut, d_{i,j}) * fb[b,j,f4] ----
    const int fq = tid & 15;     // float4 group within the 64-f row
    const int jg = tid >> 4;     // 16 groups of 16 j
    float4 acc[I_];
    #pragma unroll
    for (int ii = 0; ii < I_; ++ii) acc[ii] = make_float4(0.f, 0.f, 0.f, 0.f);

    const float* fbrow = fb + (size_t)b * N_ * F_;
    #pragma unroll 4
    for (int jj = 0; jj < 16; ++jj) {
        const int j = jg * 16 + jj;
        const float4 fv = *(const float4*)(fbrow + j * F_ + fq * 4);
        #pragma unroll
        for (int ii = 0; ii < I_; ++ii) {
            const float fi  = s_scr[ii * N_ + j];
            const int   idx = (int)fi;
            const float frac = fi - (float)idx;
            const float* p0 = s_lut + idx * F_ + fq * 4;
            const float4 L0 = *(const float4*)(p0);
            const float4 L1 = *(const float4*)(p0 + F_);
            acc[ii].x = fmaf(fmaf(frac, L1.x - L0.x, L0.x), fv.x, acc[ii].x);
            acc[ii].y = fmaf(fmaf(frac, L1.y - L0.y, L0.y), fv.y, acc[ii].y);
            acc[ii].z = fmaf(fmaf(frac, L1.z - L0.z, L0.z), fv.z, acc[ii].z);
            acc[ii].w = fmaf(fmaf(frac, L1.w - L0.w, L0.w), fv.w, acc[ii].w);
        }
    }
    __syncthreads();   // s_scr (fi) dead; reuse as partial buffer

    // ---- reduce the 16 j-groups: shfl across quarters, then 4 wave-partials in LDS ----
    #pragma unroll
    for (int ii = 0; ii < I_; ++ii) {
        acc[ii].x += __shfl_xor(acc[ii].x, 16); acc[ii].y += __shfl_xor(acc[ii].y, 16);
        acc[ii].z += __shfl_xor(acc[ii].z, 16); acc[ii].w += __shfl_xor(acc[ii].w, 16);
        acc[ii].x += __shfl_xor(acc[ii].x, 32); acc[ii].y += __shfl_xor(acc[ii].y, 32);
        acc[ii].z += __shfl_xor(acc[ii].z, 32); acc[ii].w += __shfl_xor(acc[ii].w, 32);
    }
    const int wv = tid >> 6;             // wave id 0..3
    if ((tid & 63) < 16) {
        #pragma unroll
        for (int ii = 0; ii < I_; ++ii)
            *(float4*)(s_scr + ii * N_ + wv * F_ + fq * 4) = acc[ii];
    }
    __syncthreads();

    // ---- f_bar = sp(sum of 4 wave-partials) : 256 items = 4 ii x 64 f ----
    {
        const int ii = tid >> 6, f = tid & 63;
        float s = s_scr[ii * N_ + 0 * F_ + f] + s_scr[ii * N_ + 1 * F_ + f]
                + s_scr[ii * N_ + 2 * F_ + f] + s_scr[ii * N_ + 3 * F_ + f];
        s_fbar[ii * F_ + f] = sp(s);
    }
    __syncthreads();   // s_scr (partials) dead; reuse as h2 buffer

    // ---- h2[ii][h] = sp(fbar . pc_w1[:,h] + b1[h]) : 512 items ----
    #pragma unroll
    for (int w = 0; w < 2; ++w) {
        const int item = w * 256 + tid;
        const int ii = item >> 7, h = item & 127;
        float z = pc_b1[h];
        #pragma unroll 8
        for (int f = 0; f < F_; ++f)
            z = fmaf(s_fbar[ii * F_ + f], pc_w1[f * H_ + h], z);
        s_scr[ii * H_ + h] = sp(z);
    }
    __syncthreads();

    // ---- out[ii][p] = sp(h2 . pc_w2[:,p] + b2[p]) : 64 items ----
    if (tid < I_ * FP_) {
        const int ii = tid >> 4, p = tid & 15;
        float z = pc_b2[p];
        #pragma unroll 8
        for (int h = 0; h < H_; ++h)
            z = fmaf(s_scr[ii * H_ + h], pc_w2[h * FP_ + p], z);
        out[((size_t)(b * N_ + itile + ii)) * FP_ + p] = sp(z);
    }
}

extern "C" void kernel_launch(void* const* d_in, const int* in_sizes, int n_in,
                              void* d_out, int out_size, void* d_ws, size_t ws_size,
                              hipStream_t stream) {
    const float* r_batch = (const float*)d_in[0];
    const float* f_batch = (const float*)d_in[1];
    const float* mp_w1   = (const float*)d_in[2];
    const float* mp_b1   = (const float*)d_in[3];
    const float* mp_w2   = (const float*)d_in[4];
    const float* mp_b2   = (const float*)d_in[5];
    const float* pc_w1   = (const float*)d_in[6];
    const float* pc_b1   = (const float*)d_in[7];
    const float* pc_w2   = (const float*)d_in[8];
    const float* pc_b2   = (const float*)d_in[9];
    float* out = (float*)d_out;
    float* lut = (float*)d_ws;   // T_*F_*4 = 48 KB scratch

    const float dstep    = DMAX / (float)(T_ - 1);
    const float inv_step = (float)(T_ - 1) / DMAX;

    pp_build_lut<<<T_, H_, 0, stream>>>(mp_w1, mp_b1, mp_w2, mp_b2, lut, dstep);
    pp_predict<<<B_ * N_ / I_, 256, 0, stream>>>(r_batch, f_batch, lut,
                                                 pc_w1, pc_b1, pc_w2, pc_b2,
                                                 out, inv_step);
}